// Round 6
// baseline (37.927 us; speedup 1.0000x reference)
//
#include <hip/hip_runtime.h>
#include <math.h>

typedef float nfloat4 __attribute__((ext_vector_type(4)));  // native vec for NT store

// ---------------------------------------------------------------------------
// Kernel 1: bucket proposals by 32x32-px Morton cell of their center.
// Counting sort (64 bins) -> perm[rank] = original proposal index.
// Intra-bin order nondeterminism only affects scheduling; outputs are keyed
// by the ORIGINAL index, so result bytes are exact and deterministic.
// ---------------------------------------------------------------------------
__global__ __launch_bounds__(256) void bucket_perm(
    const float4* __restrict__ props, unsigned int* __restrict__ perm, int nprop)
{
    __shared__ unsigned int hist[64];
    __shared__ unsigned int base[64];
    const int t = threadIdx.x;
    if (t < 64) hist[t] = 0u;
    __syncthreads();

    for (int i = t; i < nprop; i += 256) {
        const float4 p = props[i];
        const int cx = min(max((int)(0.5f * (p.x + p.z)), 0), 255);
        const int cy = min(max((int)(0.5f * (p.y + p.w)), 0), 255);
        const int gx = cx >> 5, gy = cy >> 5;     // 8x8 grid
        const unsigned int m = (gx & 1) | ((gy & 1) << 1) | ((gx & 2) << 1)
                             | ((gy & 2) << 2) | ((gx & 4) << 2) | ((gy & 4) << 3);
        atomicAdd(&hist[m], 1u);
    }
    __syncthreads();
    if (t == 0) {
        unsigned int s = 0;
        for (int b = 0; b < 64; ++b) { base[b] = s; s += hist[b]; }
    }
    __syncthreads();
    for (int i = t; i < nprop; i += 256) {
        const float4 p = props[i];
        const int cx = min(max((int)(0.5f * (p.x + p.z)), 0), 255);
        const int cy = min(max((int)(0.5f * (p.y + p.w)), 0), 255);
        const int gx = cx >> 5, gy = cy >> 5;
        const unsigned int m = (gx & 1) | ((gy & 1) << 1) | ((gx & 2) << 1)
                             | ((gy & 2) << 2) | ((gx & 4) << 2) | ((gy & 4) << 3);
        const unsigned int pos = atomicAdd(&base[m], 1u);
        perm[pos] = (unsigned int)i;
    }
}

// ---------------------------------------------------------------------------
// Kernel 2: TWO blocks (4 waves each) per proposal -> 8 blocks/CU (100%
// theoretical occupancy). Bijective XCD swizzle over sorted ranks keeps both
// halves of a proposal and its spatial neighbors on the same XCD-L2.
// Each wave pipelines its points 2-deep and stores non-temporally.
// ---------------------------------------------------------------------------
template<int S>
__global__ __launch_bounds__(256) void roi_block2(
    const float* __restrict__ fm,          // [H, W, 256]
    const float4* __restrict__ props,      // [nprop]
    const unsigned int* __restrict__ perm, // [nprop] sorted->orig
    float* __restrict__ out,               // [nprop, S, S, 256]
    int nprop, int H, int W)
{
    constexpr int C = 256, SS = S * S;
    constexpr int HALF0 = (SS + 1) / 2;    // 25 for S=7
    const int nblk = gridDim.x;            // 2*nprop
    const int bid = blockIdx.x;
    // bijective XCD swizzle: XCD k <- contiguous run of sorted ranks
    const int q = nblk >> 3, r = nblk & 7;
    const int xcd = bid & 7, pos = bid >> 3;
    const int rank = (xcd < r ? xcd * (q + 1) : r * (q + 1) + (xcd - r) * q) + pos;
    const int prank = rank >> 1;           // sorted proposal rank
    const int half  = rank & 1;
    if (prank >= nprop) return;
    const int n = (int)perm[prank];

    const int lane = threadIdx.x & 63;
    const int wid  = threadIdx.x >> 6;     // 0..3

    const float4 pr = props[n];
    const float x1 = fmaxf(rintf(pr.x), 0.0f);
    const float y1 = fmaxf(rintf(pr.y), 0.0f);
    const float x2 = fminf(rintf(pr.z), (float)(W - 1));
    const float y2 = fminf(rintf(pr.w), (float)(H - 1));
    const float h  = y2 - y1;
    const float w  = x2 - x1;
    const float hc = fmaxf(h - 1.0f, 0.0f);
    const float wc = fmaxf(w - 1.0f, 0.0f);

    float* outn = out + (size_t)n * SS * C;
    const int base = half ? HALF0 : 0;
    const int lim  = half ? SS : HALF0;

#define ROI_SETUP(ij_, rr_, wxo_, wyo_) {                                        \
        const int i_ = (ij_) / S, j_ = (ij_) - i_ * S;                           \
        const float sy_ = fminf(fmaxf((((float)i_ + 0.5f) / (float)S) * h - 0.5f,\
                                      0.0f), hc) + y1;                           \
        const float sx_ = fminf(fmaxf((((float)j_ + 0.5f) / (float)S) * w - 0.5f,\
                                      0.0f), wc) + x1;                           \
        const float y0f_ = floorf(sy_), x0f_ = floorf(sx_);                      \
        const int y0i_ = (int)y0f_, x0i_ = (int)x0f_;                            \
        const int y1i_ = min(y0i_ + 1, H - 1), x1i_ = min(x0i_ + 1, W - 1);      \
        wyo_ = sy_ - y0f_; wxo_ = sx_ - x0f_;                                    \
        rr_[0] = (const float4*)(fm + ((size_t)y0i_ * W + x0i_) * C);            \
        rr_[1] = (const float4*)(fm + ((size_t)y0i_ * W + x1i_) * C);            \
        rr_[2] = (const float4*)(fm + ((size_t)y1i_ * W + x0i_) * C);            \
        rr_[3] = (const float4*)(fm + ((size_t)y1i_ * W + x1i_) * C);            \
    }

    int ij = base + wid;
    if (ij >= lim) return;
    const float4* ra[4]; float wxa, wya;
    ROI_SETUP(ij, ra, wxa, wya);
    float4 va0 = ra[0][lane], va1 = ra[1][lane], va2 = ra[2][lane], va3 = ra[3][lane];

    while (true) {
        const int ijn = ij + 4;
        const bool more = (ijn < lim);
        const float4* rb[4]; float wxb = 0.f, wyb = 0.f;
        float4 vb0, vb1, vb2, vb3;
        if (more) {                                   // issue next point's loads
            ROI_SETUP(ijn, rb, wxb, wyb);
            vb0 = rb[0][lane]; vb1 = rb[1][lane]; vb2 = rb[2][lane]; vb3 = rb[3][lane];
        }
        const float owx = 1.0f - wxa, owy = 1.0f - wya;
        nfloat4 res;
        res.x = (va0.x * owx + va1.x * wxa) * owy + (va2.x * owx + va3.x * wxa) * wya;
        res.y = (va0.y * owx + va1.y * wxa) * owy + (va2.y * owx + va3.y * wxa) * wya;
        res.z = (va0.z * owx + va1.z * wxa) * owy + (va2.z * owx + va3.z * wxa) * wya;
        res.w = (va0.w * owx + va1.w * wxa) * owy + (va2.w * owx + va3.w * wxa) * wya;
        __builtin_nontemporal_store(res, (nfloat4*)(outn + (size_t)ij * C) + lane);
        if (!more) break;
        va0 = vb0; va1 = vb1; va2 = vb2; va3 = vb3;
        wxa = wxb; wya = wyb; ij = ijn;
    }
#undef ROI_SETUP
}

// Generic fallback (any S, any C multiple of 4), one wave per point.
__global__ __launch_bounds__(256) void roi_align_generic(
    const float* __restrict__ fm,
    const float* __restrict__ props,
    float* __restrict__ out,
    int S, int nprop, int H, int W, int C)
{
    const int wave = (int)((blockIdx.x * blockDim.x + threadIdx.x) >> 6);
    const int lane = threadIdx.x & 63;
    const int total = nprop * S * S;
    if (wave >= total) return;

    const int n  = wave / (S * S);
    const int ij = wave - n * (S * S);
    const int i  = ij / S;
    const int j  = ij - i * S;

    const float4 pr = ((const float4*)props)[n];
    const float x1 = fmaxf(rintf(pr.x), 0.0f);
    const float y1 = fmaxf(rintf(pr.y), 0.0f);
    const float x2 = fminf(rintf(pr.z), (float)(W - 1));
    const float y2 = fminf(rintf(pr.w), (float)(H - 1));
    const float h  = y2 - y1;
    const float w  = x2 - x1;

    const float sy = fminf(fmaxf((((float)i + 0.5f) / (float)S) * h - 0.5f, 0.0f),
                           fmaxf(h - 1.0f, 0.0f)) + y1;
    const float sx = fminf(fmaxf((((float)j + 0.5f) / (float)S) * w - 0.5f, 0.0f),
                           fmaxf(w - 1.0f, 0.0f)) + x1;

    const float y0f = floorf(sy);
    const float x0f = floorf(sx);
    const int y0i = (int)y0f;
    const int x0i = (int)x0f;
    const int y1i = min(y0i + 1, H - 1);
    const int x1i = min(x0i + 1, W - 1);
    const float wy = sy - y0f, owy = 1.0f - wy;
    const float wx = sx - x0f, owx = 1.0f - wx;

    const float4* r00 = (const float4*)(fm + ((size_t)y0i * W + x0i) * C);
    const float4* r01 = (const float4*)(fm + ((size_t)y0i * W + x1i) * C);
    const float4* r10 = (const float4*)(fm + ((size_t)y1i * W + x0i) * C);
    const float4* r11 = (const float4*)(fm + ((size_t)y1i * W + x1i) * C);
    float4* o = (float4*)(out + (size_t)wave * C);

    const int nvec = C >> 2;
    for (int v = lane; v < nvec; v += 64) {
        const float4 v00 = r00[v];
        const float4 v01 = r01[v];
        const float4 v10 = r10[v];
        const float4 v11 = r11[v];
        float4 r;
        r.x = (v00.x * owx + v01.x * wx) * owy + (v10.x * owx + v11.x * wx) * wy;
        r.y = (v00.y * owx + v01.y * wx) * owy + (v10.y * owx + v11.y * wx) * wy;
        r.z = (v00.z * owx + v01.z * wx) * owy + (v10.z * owx + v11.z * wx) * wy;
        r.w = (v00.w * owx + v01.w * wx) * owy + (v10.w * owx + v11.w * wx) * wy;
        o[v] = r;
    }
}

extern "C" void kernel_launch(void* const* d_in, const int* in_sizes, int n_in,
                              void* d_out, int out_size, void* d_ws, size_t ws_size,
                              hipStream_t stream)
{
    const float* fm    = (const float*)d_in[0];   // (1, 256, 256, 256) f32
    const float* props = (const float*)d_in[1];   // (1024, 4) f32
    float* out = (float*)d_out;

    const int H = 256, W = 256, C = 256;
    const int nprop = in_sizes[1] / 4;
    int S = 1;
    {
        const long long per = (long long)nprop * C;
        const long long ss = (long long)out_size / per;
        while ((long long)(S + 1) * (S + 1) <= ss) ++S;
    }

    if (S == 7 && C == 256 && (size_t)nprop * sizeof(unsigned int) <= ws_size) {
        unsigned int* perm = (unsigned int*)d_ws;
        bucket_perm<<<1, 256, 0, stream>>>((const float4*)props, perm, nprop);
        roi_block2<7><<<2 * nprop, 256, 0, stream>>>(fm, (const float4*)props, perm,
                                                     out, nprop, H, W);
    } else {
        const int total_waves = nprop * S * S;
        const int blocks = (total_waves + 3) / 4;
        roi_align_generic<<<blocks, 256, 0, stream>>>(fm, props, out, S, nprop, H, W, C);
    }
}

// Round 7
// 36.883 us; speedup vs baseline: 1.0283x; 1.0283x over previous
//
#include <hip/hip_runtime.h>
#include <math.h>

typedef float nfloat4 __attribute__((ext_vector_type(4)));  // native vec for NT store

// ---------------------------------------------------------------------------
// Kernel 1: bucket proposals by 32x32-px Morton cell of their center.
// Counting sort (64 bins) -> perm[rank] = original proposal index.
// Intra-bin order nondeterminism only affects scheduling; outputs are keyed
// by the ORIGINAL index, so result bytes are exact and deterministic.
// ---------------------------------------------------------------------------
__global__ __launch_bounds__(256) void bucket_perm(
    const float4* __restrict__ props, unsigned int* __restrict__ perm, int nprop)
{
    __shared__ unsigned int hist[64];
    __shared__ unsigned int base[64];
    const int t = threadIdx.x;
    if (t < 64) hist[t] = 0u;
    __syncthreads();

    for (int i = t; i < nprop; i += 256) {
        const float4 p = props[i];
        const int cx = min(max((int)(0.5f * (p.x + p.z)), 0), 255);
        const int cy = min(max((int)(0.5f * (p.y + p.w)), 0), 255);
        const int gx = cx >> 5, gy = cy >> 5;     // 8x8 grid
        const unsigned int m = (gx & 1) | ((gy & 1) << 1) | ((gx & 2) << 1)
                             | ((gy & 2) << 2) | ((gx & 4) << 2) | ((gy & 4) << 3);
        atomicAdd(&hist[m], 1u);
    }
    __syncthreads();
    if (t == 0) {
        unsigned int s = 0;
        for (int b = 0; b < 64; ++b) { base[b] = s; s += hist[b]; }
    }
    __syncthreads();
    for (int i = t; i < nprop; i += 256) {
        const float4 p = props[i];
        const int cx = min(max((int)(0.5f * (p.x + p.z)), 0), 255);
        const int cy = min(max((int)(0.5f * (p.y + p.w)), 0), 255);
        const int gx = cx >> 5, gy = cy >> 5;
        const unsigned int m = (gx & 1) | ((gy & 1) << 1) | ((gx & 2) << 1)
                             | ((gy & 2) << 2) | ((gx & 4) << 2) | ((gy & 4) << 3);
        const unsigned int pos = atomicAdd(&base[m], 1u);
        perm[pos] = (unsigned int)i;
    }
}

// ---------------------------------------------------------------------------
// Kernel 2: one block (4 waves) per proposal; XCD-bijective swizzle maps a
// contiguous run of spatially-sorted proposals onto each XCD so concurrent
// blocks share L2-resident fm pixels. Each wave pipelines its points 2-deep.
// (Measured best configuration: round-5, 36.9 us, FETCH 62 MB.)
// ---------------------------------------------------------------------------
template<int S>
__global__ __launch_bounds__(256) void roi_block(
    const float* __restrict__ fm,          // [H, W, 256]
    const float4* __restrict__ props,      // [nprop]
    const unsigned int* __restrict__ perm, // [nprop] sorted->orig
    float* __restrict__ out,               // [nprop, S, S, 256]
    int nprop, int H, int W)
{
    constexpr int C = 256, SS = S * S;
    const int nblk = gridDim.x;
    const int bid = blockIdx.x;
    // bijective XCD swizzle (m204 variant): XCD k <- contiguous sorted ranks
    const int q = nblk >> 3, r = nblk & 7;
    const int xcd = bid & 7, pos = bid >> 3;
    const int rank = (xcd < r ? xcd * (q + 1) : r * (q + 1) + (xcd - r) * q) + pos;
    if (rank >= nprop) return;
    const int n = (int)perm[rank];

    const int lane = threadIdx.x & 63;
    const int wid  = threadIdx.x >> 6;     // 0..3

    const float4 pr = props[n];
    const float x1 = fmaxf(rintf(pr.x), 0.0f);
    const float y1 = fmaxf(rintf(pr.y), 0.0f);
    const float x2 = fminf(rintf(pr.z), (float)(W - 1));
    const float y2 = fminf(rintf(pr.w), (float)(H - 1));
    const float h  = y2 - y1;
    const float w  = x2 - x1;
    const float hc = fmaxf(h - 1.0f, 0.0f);
    const float wc = fmaxf(w - 1.0f, 0.0f);

    float* outn = out + (size_t)n * SS * C;

#define ROI_SETUP(ij_, rr_, wxo_, wyo_) {                                        \
        const int i_ = (ij_) / S, j_ = (ij_) - i_ * S;                           \
        const float sy_ = fminf(fmaxf((((float)i_ + 0.5f) / (float)S) * h - 0.5f,\
                                      0.0f), hc) + y1;                           \
        const float sx_ = fminf(fmaxf((((float)j_ + 0.5f) / (float)S) * w - 0.5f,\
                                      0.0f), wc) + x1;                           \
        const float y0f_ = floorf(sy_), x0f_ = floorf(sx_);                      \
        const int y0i_ = (int)y0f_, x0i_ = (int)x0f_;                            \
        const int y1i_ = min(y0i_ + 1, H - 1), x1i_ = min(x0i_ + 1, W - 1);      \
        wyo_ = sy_ - y0f_; wxo_ = sx_ - x0f_;                                    \
        rr_[0] = (const float4*)(fm + ((size_t)y0i_ * W + x0i_) * C);            \
        rr_[1] = (const float4*)(fm + ((size_t)y0i_ * W + x1i_) * C);            \
        rr_[2] = (const float4*)(fm + ((size_t)y1i_ * W + x0i_) * C);            \
        rr_[3] = (const float4*)(fm + ((size_t)y1i_ * W + x1i_) * C);            \
    }

    int ij = wid;
    const float4* ra[4]; float wxa, wya;
    ROI_SETUP(ij, ra, wxa, wya);
    float4 va0 = ra[0][lane], va1 = ra[1][lane], va2 = ra[2][lane], va3 = ra[3][lane];

    while (true) {
        const int ijn = ij + 4;
        const bool more = (ijn < SS);
        const float4* rb[4]; float wxb = 0.f, wyb = 0.f;
        float4 vb0, vb1, vb2, vb3;
        if (more) {                                   // issue next point's loads
            ROI_SETUP(ijn, rb, wxb, wyb);
            vb0 = rb[0][lane]; vb1 = rb[1][lane]; vb2 = rb[2][lane]; vb3 = rb[3][lane];
        }
        const float owx = 1.0f - wxa, owy = 1.0f - wya;
        nfloat4 res;
        res.x = (va0.x * owx + va1.x * wxa) * owy + (va2.x * owx + va3.x * wxa) * wya;
        res.y = (va0.y * owx + va1.y * wxa) * owy + (va2.y * owx + va3.y * wxa) * wya;
        res.z = (va0.z * owx + va1.z * wxa) * owy + (va2.z * owx + va3.z * wxa) * wya;
        res.w = (va0.w * owx + va1.w * wxa) * owy + (va2.w * owx + va3.w * wxa) * wya;
        __builtin_nontemporal_store(res, (nfloat4*)(outn + (size_t)ij * C) + lane);
        if (!more) break;
        va0 = vb0; va1 = vb1; va2 = vb2; va3 = vb3;
        wxa = wxb; wya = wyb; ij = ijn;
    }
#undef ROI_SETUP
}

// Generic fallback (any S, any C multiple of 4), one wave per point.
__global__ __launch_bounds__(256) void roi_align_generic(
    const float* __restrict__ fm,
    const float* __restrict__ props,
    float* __restrict__ out,
    int S, int nprop, int H, int W, int C)
{
    const int wave = (int)((blockIdx.x * blockDim.x + threadIdx.x) >> 6);
    const int lane = threadIdx.x & 63;
    const int total = nprop * S * S;
    if (wave >= total) return;

    const int n  = wave / (S * S);
    const int ij = wave - n * (S * S);
    const int i  = ij / S;
    const int j  = ij - i * S;

    const float4 pr = ((const float4*)props)[n];
    const float x1 = fmaxf(rintf(pr.x), 0.0f);
    const float y1 = fmaxf(rintf(pr.y), 0.0f);
    const float x2 = fminf(rintf(pr.z), (float)(W - 1));
    const float y2 = fminf(rintf(pr.w), (float)(H - 1));
    const float h  = y2 - y1;
    const float w  = x2 - x1;

    const float sy = fminf(fmaxf((((float)i + 0.5f) / (float)S) * h - 0.5f, 0.0f),
                           fmaxf(h - 1.0f, 0.0f)) + y1;
    const float sx = fminf(fmaxf((((float)j + 0.5f) / (float)S) * w - 0.5f, 0.0f),
                           fmaxf(w - 1.0f, 0.0f)) + x1;

    const float y0f = floorf(sy);
    const float x0f = floorf(sx);
    const int y0i = (int)y0f;
    const int x0i = (int)x0f;
    const int y1i = min(y0i + 1, H - 1);
    const int x1i = min(x0i + 1, W - 1);
    const float wy = sy - y0f, owy = 1.0f - wy;
    const float wx = sx - x0f, owx = 1.0f - wx;

    const float4* r00 = (const float4*)(fm + ((size_t)y0i * W + x0i) * C);
    const float4* r01 = (const float4*)(fm + ((size_t)y0i * W + x1i) * C);
    const float4* r10 = (const float4*)(fm + ((size_t)y1i * W + x0i) * C);
    const float4* r11 = (const float4*)(fm + ((size_t)y1i * W + x1i) * C);
    float4* o = (float4*)(out + (size_t)wave * C);

    const int nvec = C >> 2;
    for (int v = lane; v < nvec; v += 64) {
        const float4 v00 = r00[v];
        const float4 v01 = r01[v];
        const float4 v10 = r10[v];
        const float4 v11 = r11[v];
        float4 r;
        r.x = (v00.x * owx + v01.x * wx) * owy + (v10.x * owx + v11.x * wx) * wy;
        r.y = (v00.y * owx + v01.y * wx) * owy + (v10.y * owx + v11.y * wx) * wy;
        r.z = (v00.z * owx + v01.z * wx) * owy + (v10.z * owx + v11.z * wx) * wy;
        r.w = (v00.w * owx + v01.w * wx) * owy + (v10.w * owx + v11.w * wx) * wy;
        o[v] = r;
    }
}

extern "C" void kernel_launch(void* const* d_in, const int* in_sizes, int n_in,
                              void* d_out, int out_size, void* d_ws, size_t ws_size,
                              hipStream_t stream)
{
    const float* fm    = (const float*)d_in[0];   // (1, 256, 256, 256) f32
    const float* props = (const float*)d_in[1];   // (1024, 4) f32
    float* out = (float*)d_out;

    const int H = 256, W = 256, C = 256;
    const int nprop = in_sizes[1] / 4;
    int S = 1;
    {
        const long long per = (long long)nprop * C;
        const long long ss = (long long)out_size / per;
        while ((long long)(S + 1) * (S + 1) <= ss) ++S;
    }

    if (S == 7 && C == 256 && (size_t)nprop * sizeof(unsigned int) <= ws_size) {
        unsigned int* perm = (unsigned int*)d_ws;
        bucket_perm<<<1, 256, 0, stream>>>((const float4*)props, perm, nprop);
        roi_block<7><<<nprop, 256, 0, stream>>>(fm, (const float4*)props, perm,
                                                out, nprop, H, W);
    } else {
        const int total_waves = nprop * S * S;
        const int blocks = (total_waves + 3) / 4;
        roi_align_generic<<<blocks, 256, 0, stream>>>(fm, props, out, S, nprop, H, W, C);
    }
}